// Round 3
// baseline (483.717 us; speedup 1.0000x reference)
//
#include <hip/hip_runtime.h>
#include <hip/hip_cooperative_groups.h>

namespace cg = cooperative_groups;

#define D  128
#define NT 256
#define NB 1024   // 4 blocks/CU x 256 CUs; __launch_bounds__(256,4) guarantees residency

typedef __attribute__((ext_vector_type(4))) _Float16 half4;

__device__ __forceinline__ float4 elu_mul(float4 g, float4 w) {
    float4 v;
    v.x = g.x * w.x; v.y = g.y * w.y; v.z = g.z * w.z; v.w = g.w * w.w;
    v.x = (v.x > 0.0f) ? v.x : (__expf(v.x) - 1.0f);
    v.y = (v.y > 0.0f) ? v.y : (__expf(v.y) - 1.0f);
    v.z = (v.z > 0.0f) ? v.z : (__expf(v.z) - 1.0f);
    v.w = (v.w > 0.0f) ? v.w : (__expf(v.w) - 1.0f);
    return v;
}

// ---------------------------------------------------------------------------
// Cooperative preprocessing: emb(fp16) + zero counts | hist+rank | scan | fill
// ---------------------------------------------------------------------------
__global__ __launch_bounds__(NT, 4)
void pre_kernel(const float* __restrict__ ge, const float* __restrict__ weight,
                const int* __restrict__ e_feat, const int* __restrict__ src,
                const int* __restrict__ dst,
                _Float16* __restrict__ emb, int* __restrict__ counts,
                int* __restrict__ offsets, int* __restrict__ rank,
                unsigned int* __restrict__ bucket, int* __restrict__ bsum,
                int n_nodes, int n_edges) {
    cg::grid_group grid = cg::this_grid();
    __shared__ int s[NT];
    const int tid = blockIdx.x * NT + threadIdx.x;
    const int nthr = NB * NT;

    // --- Phase A: zero counts + compute emb = elu(ge*w) in fp16 -------------
    for (int i = tid; i < n_nodes; i += nthr) counts[i] = 0;
    const int quads = n_nodes * (D / 4);
    for (int q = tid; q < quads; q += nthr) {
        int col = (q & 31) * 4;  // 32 quads per row
        float4 g = *reinterpret_cast<const float4*>(ge + (size_t)q * 4);
        float4 w = *reinterpret_cast<const float4*>(weight + col);
        float4 v = elu_mul(g, w);
        half4 h;
        h.x = (_Float16)v.x; h.y = (_Float16)v.y;
        h.z = (_Float16)v.z; h.w = (_Float16)v.w;
        *reinterpret_cast<half4*>(emb + (size_t)q * 4) = h;
    }
    grid.sync();

    // --- Phase B: histogram of dst, recording each edge's rank --------------
    for (int e = tid; e < n_edges; e += nthr)
        rank[e] = atomicAdd(&counts[dst[e]], 1);
    grid.sync();

    // --- Phase C1: per-chunk exclusive scan (256/chunk) ---------------------
    const int nchunks = (n_nodes + NT - 1) / NT;  // 196 <= NT
    if (blockIdx.x < nchunks) {
        int t = threadIdx.x;
        int idx = blockIdx.x * NT + t;
        int v = (idx < n_nodes) ? counts[idx] : 0;
        s[t] = v;
        __syncthreads();
        for (int d = 1; d < NT; d <<= 1) {
            int x = (t >= d) ? s[t - d] : 0;
            __syncthreads();
            s[t] += x;
            __syncthreads();
        }
        if (idx < n_nodes) offsets[idx] = s[t] - v;  // chunk-local exclusive
        if (t == NT - 1) bsum[blockIdx.x] = s[t];    // chunk total
    }
    grid.sync();

    // --- Phase C2: scan chunk totals (redundantly per block), add prefix ----
    if (blockIdx.x < nchunks) {
        int t = threadIdx.x;
        int v = (t < nchunks) ? bsum[t] : 0;
        s[t] = v;
        __syncthreads();
        for (int d = 1; d < NT; d <<= 1) {
            int x = (t >= d) ? s[t - d] : 0;
            __syncthreads();
            s[t] += x;
            __syncthreads();
        }
        int prefix = s[blockIdx.x] - bsum[blockIdx.x];  // exclusive prefix of my chunk
        int idx = blockIdx.x * NT + t;
        if (idx < n_nodes) offsets[idx] += prefix;
        if (blockIdx.x == 0 && t == 0) offsets[n_nodes] = n_edges;
    }
    grid.sync();

    // --- Phase D: atomic-free bucket fill -----------------------------------
    for (int e = tid; e < n_edges; e += nthr) {
        int ef = e_feat[e];
        unsigned int flag = (ef == 0 || ef == 6 || ef == 14 || ef == 30) ? 1u : 0u;
        int pos = offsets[dst[e]] + rank[e];
        bucket[pos] = (unsigned int)src[e] | (flag << 31);
    }
}

// ---------------------------------------------------------------------------
// Gather: 32 lanes/node, 4 fp16 cols/lane (8 B), 4x unrolled edge loop.
// ---------------------------------------------------------------------------
__global__ __launch_bounds__(256)
void gather_kernel(const _Float16* __restrict__ emb,
                   const int* __restrict__ offsets,
                   const unsigned int* __restrict__ bucket,
                   float* __restrict__ out, int n_nodes) {
    int tid = blockIdx.x * 256 + threadIdx.x;
    int node = tid >> 5;
    if (node >= n_nodes) return;
    int col = (tid & 31) * 4;

    float4 acc = make_float4(0.f, 0.f, 0.f, 0.f);
    int beg = offsets[node];
    int end = offsets[node + 1];

    int i = beg;
    for (; i + 4 <= end; i += 4) {
        unsigned int r0 = bucket[i + 0], r1 = bucket[i + 1];
        unsigned int r2 = bucket[i + 2], r3 = bucket[i + 3];
        half4 h0 = *reinterpret_cast<const half4*>(emb + (size_t)(r0 & 0x7FFFFFFFu) * D + col);
        half4 h1 = *reinterpret_cast<const half4*>(emb + (size_t)(r1 & 0x7FFFFFFFu) * D + col);
        half4 h2 = *reinterpret_cast<const half4*>(emb + (size_t)(r2 & 0x7FFFFFFFu) * D + col);
        half4 h3 = *reinterpret_cast<const half4*>(emb + (size_t)(r3 & 0x7FFFFFFFu) * D + col);
        float m0 = (r0 >> 31) ? 2.0f : 1.0f;
        float m1 = (r1 >> 31) ? 2.0f : 1.0f;
        float m2 = (r2 >> 31) ? 2.0f : 1.0f;
        float m3 = (r3 >> 31) ? 2.0f : 1.0f;
        acc.x += (float)h0.x * m0; acc.y += (float)h0.y * m0;
        acc.z += (float)h0.z * m0; acc.w += (float)h0.w * m0;
        acc.x += (float)h1.x * m1; acc.y += (float)h1.y * m1;
        acc.z += (float)h1.z * m1; acc.w += (float)h1.w * m1;
        acc.x += (float)h2.x * m2; acc.y += (float)h2.y * m2;
        acc.z += (float)h2.z * m2; acc.w += (float)h2.w * m2;
        acc.x += (float)h3.x * m3; acc.y += (float)h3.y * m3;
        acc.z += (float)h3.z * m3; acc.w += (float)h3.w * m3;
    }
    for (; i < end; ++i) {
        unsigned int r = bucket[i];
        half4 h = *reinterpret_cast<const half4*>(emb + (size_t)(r & 0x7FFFFFFFu) * D + col);
        float m = (r >> 31) ? 2.0f : 1.0f;
        acc.x += (float)h.x * m; acc.y += (float)h.y * m;
        acc.z += (float)h.z * m; acc.w += (float)h.w * m;
    }

    *reinterpret_cast<float4*>(out + (size_t)node * D + col) = acc;
}

// ---------------------------------------------------------------------------
// Fallback (tiny workspace): round-1 atomic scatter. Only used if ws_size is
// too small for the CSR path.
// ---------------------------------------------------------------------------
__global__ void edge_scatter_fallback(const float* __restrict__ ge,
                                      const float* __restrict__ weight,
                                      const int* __restrict__ e_feat,
                                      const int* __restrict__ src,
                                      const int* __restrict__ dst,
                                      float* __restrict__ out, int n_edges) {
    long long tid = (long long)blockIdx.x * blockDim.x + threadIdx.x;
    int edge = (int)(tid >> 5);
    if (edge >= n_edges) return;
    int col = (int)(tid & 31) * 4;
    int e = e_feat[edge];
    float mult = (e == 0 || e == 6 || e == 14 || e == 30) ? 2.0f : 1.0f;
    float4 w = *reinterpret_cast<const float4*>(weight + col);
    float4 g = *reinterpret_cast<const float4*>(ge + (long long)src[edge] * D + col);
    float4 v = elu_mul(g, w);
    float* o = out + (long long)dst[edge] * D + col;
    atomicAdd(o + 0, v.x * mult);
    atomicAdd(o + 1, v.y * mult);
    atomicAdd(o + 2, v.z * mult);
    atomicAdd(o + 3, v.w * mult);
}

extern "C" void kernel_launch(void* const* d_in, const int* in_sizes, int n_in,
                              void* d_out, int out_size, void* d_ws, size_t ws_size,
                              hipStream_t stream) {
    const float* ge     = (const float*)d_in[0];   // [N, 128]
    const float* weight = (const float*)d_in[1];   // [1, 128]
    const int*   e_feat = (const int*)d_in[2];     // [E]
    const int*   src    = (const int*)d_in[3];     // [E]
    const int*   dst    = (const int*)d_in[4];     // [E]
    float* out = (float*)d_out;                    // [N, 128]

    int n_edges = in_sizes[2];
    int n_nodes = out_size / D;

    // Workspace layout: emb | counts | offsets | rank | bucket | bsum
    auto align256 = [](size_t x) { return (x + 255) & ~(size_t)255; };
    size_t o_emb    = 0;
    size_t o_counts = o_emb    + align256((size_t)n_nodes * D * sizeof(_Float16));
    size_t o_offs   = o_counts + align256((size_t)n_nodes * 4);
    size_t o_rank   = o_offs   + align256((size_t)(n_nodes + 1) * 4);
    size_t o_bucket = o_rank   + align256((size_t)n_edges * 4);
    size_t o_bsum   = o_bucket + align256((size_t)n_edges * 4);
    size_t need     = o_bsum + 4096;

    int nchunks = (n_nodes + NT - 1) / NT;

    if (ws_size < need || nchunks > NT) {
        // Fallback: atomic scatter, no workspace needed.
        hipMemsetAsync(d_out, 0, (size_t)out_size * sizeof(float), stream);
        long long total = (long long)n_edges * 32;
        edge_scatter_fallback<<<(int)((total + 255) / 256), 256, 0, stream>>>(
            ge, weight, e_feat, src, dst, out, n_edges);
        return;
    }

    char* ws = (char*)d_ws;
    _Float16*     emb     = (_Float16*)(ws + o_emb);
    int*          counts  = (int*)(ws + o_counts);
    int*          offsets = (int*)(ws + o_offs);
    int*          rank    = (int*)(ws + o_rank);
    unsigned int* bucket  = (unsigned int*)(ws + o_bucket);
    int*          bsum    = (int*)(ws + o_bsum);

    void* args[] = {(void*)&ge, (void*)&weight, (void*)&e_feat, (void*)&src,
                    (void*)&dst, (void*)&emb, (void*)&counts, (void*)&offsets,
                    (void*)&rank, (void*)&bucket, (void*)&bsum,
                    (void*)&n_nodes, (void*)&n_edges};
    hipLaunchCooperativeKernel((void*)pre_kernel, dim3(NB), dim3(NT), args, 0, stream);

    long long total = (long long)n_nodes * 32;
    gather_kernel<<<(int)((total + 255) / 256), 256, 0, stream>>>(
        emb, offsets, bucket, out, n_nodes);
}

// Round 4
// 86.748 us; speedup vs baseline: 5.5761x; 5.5761x over previous
//
#include <hip/hip_runtime.h>

#define D  128
#define NT 256

typedef __attribute__((ext_vector_type(4))) _Float16 half4;

__device__ __forceinline__ float4 elu_mul(float4 g, float4 w) {
    float4 v;
    v.x = g.x * w.x; v.y = g.y * w.y; v.z = g.z * w.z; v.w = g.w * w.w;
    v.x = (v.x > 0.0f) ? v.x : (__expf(v.x) - 1.0f);
    v.y = (v.y > 0.0f) ? v.y : (__expf(v.y) - 1.0f);
    v.z = (v.z > 0.0f) ? v.z : (__expf(v.z) - 1.0f);
    v.w = (v.w > 0.0f) ? v.w : (__expf(v.w) - 1.0f);
    return v;
}

// ---------------------------------------------------------------------------
// K1: zero counts + emb = elu(ge*w) in fp16 (grid-stride)
// ---------------------------------------------------------------------------
__global__ __launch_bounds__(NT)
void emb_zero_kernel(const float* __restrict__ ge, const float* __restrict__ weight,
                     _Float16* __restrict__ emb, int* __restrict__ counts,
                     int n_nodes) {
    int tid = blockIdx.x * NT + threadIdx.x;
    int nthr = gridDim.x * NT;
    for (int i = tid; i < n_nodes; i += nthr) counts[i] = 0;
    int quads = n_nodes * (D / 4);
    for (int q = tid; q < quads; q += nthr) {
        int col = (q & 31) * 4;  // 32 quads per row
        float4 g = *reinterpret_cast<const float4*>(ge + (size_t)q * 4);
        float4 w = *reinterpret_cast<const float4*>(weight + col);
        float4 v = elu_mul(g, w);
        half4 h;
        h.x = (_Float16)v.x; h.y = (_Float16)v.y;
        h.z = (_Float16)v.z; h.w = (_Float16)v.w;
        *reinterpret_cast<half4*>(emb + (size_t)q * 4) = h;
    }
}

// ---------------------------------------------------------------------------
// K2: histogram of dst, recording each edge's intra-bucket rank
// ---------------------------------------------------------------------------
__global__ __launch_bounds__(NT)
void hist_rank_kernel(const int* __restrict__ dst, int* __restrict__ counts,
                      int* __restrict__ rank, int n_edges) {
    int i = blockIdx.x * NT + threadIdx.x;
    if (i < n_edges) rank[i] = atomicAdd(&counts[dst[i]], 1);
}

// ---------------------------------------------------------------------------
// K3a: per-chunk exclusive scan (256/chunk) + chunk totals
// ---------------------------------------------------------------------------
__global__ __launch_bounds__(NT)
void scan1_kernel(const int* __restrict__ counts, int* __restrict__ offsets,
                  int* __restrict__ bsum, int n_nodes) {
    __shared__ int s[NT];
    int t = threadIdx.x;
    int idx = blockIdx.x * NT + t;
    int v = (idx < n_nodes) ? counts[idx] : 0;
    s[t] = v;
    __syncthreads();
    for (int d = 1; d < NT; d <<= 1) {
        int x = (t >= d) ? s[t - d] : 0;
        __syncthreads();
        s[t] += x;
        __syncthreads();
    }
    if (idx < n_nodes) offsets[idx] = s[t] - v;
    if (t == NT - 1) bsum[blockIdx.x] = s[t];
}

// ---------------------------------------------------------------------------
// K3b: exclusive scan of chunk totals (single block, nchunks <= 256)
// ---------------------------------------------------------------------------
__global__ __launch_bounds__(NT)
void scan2_kernel(int* __restrict__ bsum, int nchunks) {
    __shared__ int s[NT];
    int t = threadIdx.x;
    int v = (t < nchunks) ? bsum[t] : 0;
    s[t] = v;
    __syncthreads();
    for (int d = 1; d < NT; d <<= 1) {
        int x = (t >= d) ? s[t - d] : 0;
        __syncthreads();
        s[t] += x;
        __syncthreads();
    }
    if (t < nchunks) bsum[t] = s[t] - v;
}

// ---------------------------------------------------------------------------
// K3c: add chunk prefixes; offsets[N] = E
// ---------------------------------------------------------------------------
__global__ __launch_bounds__(NT)
void scan3_kernel(int* __restrict__ offsets, const int* __restrict__ bsum,
                  int n_nodes, int n_edges) {
    int idx = blockIdx.x * NT + threadIdx.x;
    if (idx < n_nodes) offsets[idx] += bsum[blockIdx.x];
    if (idx == 0) offsets[n_nodes] = n_edges;
}

// ---------------------------------------------------------------------------
// K4: atomic-free bucket fill via offsets[dst] + rank
// ---------------------------------------------------------------------------
__global__ __launch_bounds__(NT)
void fill_kernel(const int* __restrict__ e_feat, const int* __restrict__ src,
                 const int* __restrict__ dst, const int* __restrict__ offsets,
                 const int* __restrict__ rank, unsigned int* __restrict__ bucket,
                 int n_edges) {
    int i = blockIdx.x * NT + threadIdx.x;
    if (i >= n_edges) return;
    int ef = e_feat[i];
    unsigned int flag = (ef == 0 || ef == 6 || ef == 14 || ef == 30) ? 1u : 0u;
    bucket[offsets[dst[i]] + rank[i]] = (unsigned int)src[i] | (flag << 31);
}

// ---------------------------------------------------------------------------
// K5: gather. 32 lanes/node, 4 fp16 cols/lane (8 B), 4x unrolled edge loop.
// ---------------------------------------------------------------------------
__global__ __launch_bounds__(NT)
void gather_kernel(const _Float16* __restrict__ emb,
                   const int* __restrict__ offsets,
                   const unsigned int* __restrict__ bucket,
                   float* __restrict__ out, int n_nodes) {
    int tid = blockIdx.x * NT + threadIdx.x;
    int node = tid >> 5;
    if (node >= n_nodes) return;
    int col = (tid & 31) * 4;

    float4 acc = make_float4(0.f, 0.f, 0.f, 0.f);
    int beg = offsets[node];
    int end = offsets[node + 1];

    int i = beg;
    for (; i + 4 <= end; i += 4) {
        unsigned int r0 = bucket[i + 0], r1 = bucket[i + 1];
        unsigned int r2 = bucket[i + 2], r3 = bucket[i + 3];
        half4 h0 = *reinterpret_cast<const half4*>(emb + (size_t)(r0 & 0x7FFFFFFFu) * D + col);
        half4 h1 = *reinterpret_cast<const half4*>(emb + (size_t)(r1 & 0x7FFFFFFFu) * D + col);
        half4 h2 = *reinterpret_cast<const half4*>(emb + (size_t)(r2 & 0x7FFFFFFFu) * D + col);
        half4 h3 = *reinterpret_cast<const half4*>(emb + (size_t)(r3 & 0x7FFFFFFFu) * D + col);
        float m0 = (r0 >> 31) ? 2.0f : 1.0f;
        float m1 = (r1 >> 31) ? 2.0f : 1.0f;
        float m2 = (r2 >> 31) ? 2.0f : 1.0f;
        float m3 = (r3 >> 31) ? 2.0f : 1.0f;
        acc.x += (float)h0.x * m0; acc.y += (float)h0.y * m0;
        acc.z += (float)h0.z * m0; acc.w += (float)h0.w * m0;
        acc.x += (float)h1.x * m1; acc.y += (float)h1.y * m1;
        acc.z += (float)h1.z * m1; acc.w += (float)h1.w * m1;
        acc.x += (float)h2.x * m2; acc.y += (float)h2.y * m2;
        acc.z += (float)h2.z * m2; acc.w += (float)h2.w * m2;
        acc.x += (float)h3.x * m3; acc.y += (float)h3.y * m3;
        acc.z += (float)h3.z * m3; acc.w += (float)h3.w * m3;
    }
    for (; i < end; ++i) {
        unsigned int r = bucket[i];
        half4 h = *reinterpret_cast<const half4*>(emb + (size_t)(r & 0x7FFFFFFFu) * D + col);
        float m = (r >> 31) ? 2.0f : 1.0f;
        acc.x += (float)h.x * m; acc.y += (float)h.y * m;
        acc.z += (float)h.z * m; acc.w += (float)h.w * m;
    }

    *reinterpret_cast<float4*>(out + (size_t)node * D + col) = acc;
}

// ---------------------------------------------------------------------------
// Fallback (tiny workspace): round-1 atomic scatter.
// ---------------------------------------------------------------------------
__global__ void edge_scatter_fallback(const float* __restrict__ ge,
                                      const float* __restrict__ weight,
                                      const int* __restrict__ e_feat,
                                      const int* __restrict__ src,
                                      const int* __restrict__ dst,
                                      float* __restrict__ out, int n_edges) {
    long long tid = (long long)blockIdx.x * blockDim.x + threadIdx.x;
    int edge = (int)(tid >> 5);
    if (edge >= n_edges) return;
    int col = (int)(tid & 31) * 4;
    int e = e_feat[edge];
    float mult = (e == 0 || e == 6 || e == 14 || e == 30) ? 2.0f : 1.0f;
    float4 w = *reinterpret_cast<const float4*>(weight + col);
    float4 g = *reinterpret_cast<const float4*>(ge + (long long)src[edge] * D + col);
    float4 v = elu_mul(g, w);
    float* o = out + (long long)dst[edge] * D + col;
    atomicAdd(o + 0, v.x * mult);
    atomicAdd(o + 1, v.y * mult);
    atomicAdd(o + 2, v.z * mult);
    atomicAdd(o + 3, v.w * mult);
}

extern "C" void kernel_launch(void* const* d_in, const int* in_sizes, int n_in,
                              void* d_out, int out_size, void* d_ws, size_t ws_size,
                              hipStream_t stream) {
    const float* ge     = (const float*)d_in[0];   // [N, 128]
    const float* weight = (const float*)d_in[1];   // [1, 128]
    const int*   e_feat = (const int*)d_in[2];     // [E]
    const int*   src    = (const int*)d_in[3];     // [E]
    const int*   dst    = (const int*)d_in[4];     // [E]
    float* out = (float*)d_out;                    // [N, 128]

    int n_edges = in_sizes[2];
    int n_nodes = out_size / D;

    // Workspace: emb | counts | offsets | rank | bucket | bsum
    auto align256 = [](size_t x) { return (x + 255) & ~(size_t)255; };
    size_t o_emb    = 0;
    size_t o_counts = o_emb    + align256((size_t)n_nodes * D * sizeof(_Float16));
    size_t o_offs   = o_counts + align256((size_t)n_nodes * 4);
    size_t o_rank   = o_offs   + align256((size_t)(n_nodes + 1) * 4);
    size_t o_bucket = o_rank   + align256((size_t)n_edges * 4);
    size_t o_bsum   = o_bucket + align256((size_t)n_edges * 4);
    size_t need     = o_bsum + 4096;

    int nchunks = (n_nodes + NT - 1) / NT;  // 196 for N=50000

    if (ws_size < need || nchunks > NT) {
        hipMemsetAsync(d_out, 0, (size_t)out_size * sizeof(float), stream);
        long long total = (long long)n_edges * 32;
        edge_scatter_fallback<<<(int)((total + 255) / 256), 256, 0, stream>>>(
            ge, weight, e_feat, src, dst, out, n_edges);
        return;
    }

    char* ws = (char*)d_ws;
    _Float16*     emb     = (_Float16*)(ws + o_emb);
    int*          counts  = (int*)(ws + o_counts);
    int*          offsets = (int*)(ws + o_offs);
    int*          rank    = (int*)(ws + o_rank);
    unsigned int* bucket  = (unsigned int*)(ws + o_bucket);
    int*          bsum    = (int*)(ws + o_bsum);

    int eb = (n_edges + NT - 1) / NT;

    emb_zero_kernel<<<2048, NT, 0, stream>>>(ge, weight, emb, counts, n_nodes);
    hist_rank_kernel<<<eb, NT, 0, stream>>>(dst, counts, rank, n_edges);
    scan1_kernel<<<nchunks, NT, 0, stream>>>(counts, offsets, bsum, n_nodes);
    scan2_kernel<<<1, NT, 0, stream>>>(bsum, nchunks);
    scan3_kernel<<<nchunks, NT, 0, stream>>>(offsets, bsum, n_nodes, n_edges);
    fill_kernel<<<eb, NT, 0, stream>>>(e_feat, src, dst, offsets, rank, bucket, n_edges);

    long long total = (long long)n_nodes * 32;
    gather_kernel<<<(int)((total + 255) / 256), NT, 0, stream>>>(
        emb, offsets, bucket, out, n_nodes);
}

// Round 5
// 79.532 us; speedup vs baseline: 6.0821x; 1.0907x over previous
//
#include <hip/hip_runtime.h>

#define D        128
#define NT       256
#define CAP      128      // per-dst bucket capacity (avg degree 12.8, max ~30)
#define OVF_CAP  65536    // overflow list capacity (never used for this input)

typedef __attribute__((ext_vector_type(4))) _Float16 half4;

__device__ __forceinline__ float4 elu_mul(float4 g, float4 w) {
    float4 v;
    v.x = g.x * w.x; v.y = g.y * w.y; v.z = g.z * w.z; v.w = g.w * w.w;
    v.x = (v.x > 0.0f) ? v.x : (__expf(v.x) - 1.0f);
    v.y = (v.y > 0.0f) ? v.y : (__expf(v.y) - 1.0f);
    v.z = (v.z > 0.0f) ? v.z : (__expf(v.z) - 1.0f);
    v.w = (v.w > 0.0f) ? v.w : (__expf(v.w) - 1.0f);
    return v;
}

// ---------------------------------------------------------------------------
// Fused preprocessing: blocks [0, eb) bucket the edges (hist + direct fill),
// blocks [eb, grid) build emb = elu(ge*w) in fp16. The two partitions are
// independent; running them in one dispatch overlaps their memory traffic.
// ---------------------------------------------------------------------------
__global__ __launch_bounds__(NT)
void fused_pre_kernel(const float* __restrict__ ge, const float* __restrict__ weight,
                      const int* __restrict__ e_feat, const int* __restrict__ src,
                      const int* __restrict__ dst,
                      _Float16* __restrict__ emb, int* __restrict__ counts,
                      unsigned int* __restrict__ bucket,
                      int* __restrict__ ovf_cnt, int* __restrict__ ovf,
                      int n_nodes, int n_edges, int eb) {
    if ((int)blockIdx.x < eb) {
        // --- edge partition: scatter records into fixed-capacity buckets ---
        int tid = blockIdx.x * NT + threadIdx.x;
        int nthr = eb * NT;
        for (int e = tid; e < n_edges; e += nthr) {
            int d  = dst[e];
            int ef = e_feat[e];
            unsigned int flag = (ef == 0 || ef == 6 || ef == 14 || ef == 30) ? 1u : 0u;
            unsigned int rec  = (unsigned int)src[e] | (flag << 31);
            int pos = atomicAdd(&counts[d], 1);
            if (pos < CAP) {
                bucket[(size_t)d * CAP + pos] = rec;
            } else {
                int op = atomicAdd(ovf_cnt, 1);
                if (op < OVF_CAP) { ovf[2 * op] = d; ovf[2 * op + 1] = (int)rec; }
            }
        }
    } else {
        // --- emb partition: emb = elu(ge*w) in fp16, grid-stride ---
        int tid = (blockIdx.x - eb) * NT + threadIdx.x;
        int nthr = (gridDim.x - eb) * NT;
        int quads = n_nodes * (D / 4);
        for (int q = tid; q < quads; q += nthr) {
            int col = (q & 31) * 4;  // 32 quads per row
            float4 g = *reinterpret_cast<const float4*>(ge + (size_t)q * 4);
            float4 w = *reinterpret_cast<const float4*>(weight + col);
            float4 v = elu_mul(g, w);
            half4 h;
            h.x = (_Float16)v.x; h.y = (_Float16)v.y;
            h.z = (_Float16)v.z; h.w = (_Float16)v.w;
            *reinterpret_cast<half4*>(emb + (size_t)q * 4) = h;
        }
    }
}

// ---------------------------------------------------------------------------
// Gather: 32 lanes/node, 4 fp16 cols/lane, uint4 record loads (4 edges/load).
// Overflow list handled inline (expected empty -> one broadcast load).
// ---------------------------------------------------------------------------
__global__ __launch_bounds__(NT)
void gather_kernel(const _Float16* __restrict__ emb,
                   const int* __restrict__ counts,
                   const unsigned int* __restrict__ bucket,
                   const int* __restrict__ ovf_cnt, const int* __restrict__ ovf,
                   float* __restrict__ out, int n_nodes) {
    int tid = blockIdx.x * NT + threadIdx.x;
    int node = tid >> 5;
    if (node >= n_nodes) return;
    int col = (tid & 31) * 4;

    float4 acc = make_float4(0.f, 0.f, 0.f, 0.f);
    int cnt = counts[node];
    if (cnt > CAP) cnt = CAP;
    const unsigned int* bkt = bucket + (size_t)node * CAP;

    int i = 0;
    for (; i + 4 <= cnt; i += 4) {
        uint4 r = *reinterpret_cast<const uint4*>(bkt + i);  // broadcast 16 B
        half4 h0 = *reinterpret_cast<const half4*>(emb + (size_t)(r.x & 0x7FFFFFFFu) * D + col);
        half4 h1 = *reinterpret_cast<const half4*>(emb + (size_t)(r.y & 0x7FFFFFFFu) * D + col);
        half4 h2 = *reinterpret_cast<const half4*>(emb + (size_t)(r.z & 0x7FFFFFFFu) * D + col);
        half4 h3 = *reinterpret_cast<const half4*>(emb + (size_t)(r.w & 0x7FFFFFFFu) * D + col);
        float m0 = (r.x >> 31) ? 2.0f : 1.0f;
        float m1 = (r.y >> 31) ? 2.0f : 1.0f;
        float m2 = (r.z >> 31) ? 2.0f : 1.0f;
        float m3 = (r.w >> 31) ? 2.0f : 1.0f;
        acc.x += (float)h0.x * m0; acc.y += (float)h0.y * m0;
        acc.z += (float)h0.z * m0; acc.w += (float)h0.w * m0;
        acc.x += (float)h1.x * m1; acc.y += (float)h1.y * m1;
        acc.z += (float)h1.z * m1; acc.w += (float)h1.w * m1;
        acc.x += (float)h2.x * m2; acc.y += (float)h2.y * m2;
        acc.z += (float)h2.z * m2; acc.w += (float)h2.w * m2;
        acc.x += (float)h3.x * m3; acc.y += (float)h3.y * m3;
        acc.z += (float)h3.z * m3; acc.w += (float)h3.w * m3;
    }
    for (; i < cnt; ++i) {
        unsigned int r = bkt[i];
        half4 h = *reinterpret_cast<const half4*>(emb + (size_t)(r & 0x7FFFFFFFu) * D + col);
        float m = (r >> 31) ? 2.0f : 1.0f;
        acc.x += (float)h.x * m; acc.y += (float)h.y * m;
        acc.z += (float)h.z * m; acc.w += (float)h.w * m;
    }

    // Overflow (correctness guard; expected count == 0 for this input)
    int no = *ovf_cnt;
    if (no > 0) {
        if (no > OVF_CAP) no = OVF_CAP;
        for (int k = 0; k < no; ++k) {
            if (ovf[2 * k] == node) {
                unsigned int r = (unsigned int)ovf[2 * k + 1];
                half4 h = *reinterpret_cast<const half4*>(emb + (size_t)(r & 0x7FFFFFFFu) * D + col);
                float m = (r >> 31) ? 2.0f : 1.0f;
                acc.x += (float)h.x * m; acc.y += (float)h.y * m;
                acc.z += (float)h.z * m; acc.w += (float)h.w * m;
            }
        }
    }

    *reinterpret_cast<float4*>(out + (size_t)node * D + col) = acc;
}

// ---------------------------------------------------------------------------
// Fallback (tiny workspace): atomic scatter, no workspace needed.
// ---------------------------------------------------------------------------
__global__ void edge_scatter_fallback(const float* __restrict__ ge,
                                      const float* __restrict__ weight,
                                      const int* __restrict__ e_feat,
                                      const int* __restrict__ src,
                                      const int* __restrict__ dst,
                                      float* __restrict__ out, int n_edges) {
    long long tid = (long long)blockIdx.x * blockDim.x + threadIdx.x;
    int edge = (int)(tid >> 5);
    if (edge >= n_edges) return;
    int col = (int)(tid & 31) * 4;
    int e = e_feat[edge];
    float mult = (e == 0 || e == 6 || e == 14 || e == 30) ? 2.0f : 1.0f;
    float4 w = *reinterpret_cast<const float4*>(weight + col);
    float4 g = *reinterpret_cast<const float4*>(ge + (long long)src[edge] * D + col);
    float4 v = elu_mul(g, w);
    float* o = out + (long long)dst[edge] * D + col;
    atomicAdd(o + 0, v.x * mult);
    atomicAdd(o + 1, v.y * mult);
    atomicAdd(o + 2, v.z * mult);
    atomicAdd(o + 3, v.w * mult);
}

extern "C" void kernel_launch(void* const* d_in, const int* in_sizes, int n_in,
                              void* d_out, int out_size, void* d_ws, size_t ws_size,
                              hipStream_t stream) {
    const float* ge     = (const float*)d_in[0];   // [N, 128]
    const float* weight = (const float*)d_in[1];   // [1, 128]
    const int*   e_feat = (const int*)d_in[2];     // [E]
    const int*   src    = (const int*)d_in[3];     // [E]
    const int*   dst    = (const int*)d_in[4];     // [E]
    float* out = (float*)d_out;                    // [N, 128]

    int n_edges = in_sizes[2];
    int n_nodes = out_size / D;

    // Workspace: emb | counts | ovf_cnt | bucket | ovf
    auto align256 = [](size_t x) { return (x + 255) & ~(size_t)255; };
    size_t o_emb    = 0;
    size_t o_counts = o_emb    + align256((size_t)n_nodes * D * sizeof(_Float16));
    size_t o_ovfcnt = o_counts + align256((size_t)n_nodes * 4);
    size_t o_bucket = o_ovfcnt + 256;
    size_t o_ovf    = o_bucket + align256((size_t)n_nodes * CAP * 4);
    size_t need     = o_ovf + (size_t)OVF_CAP * 8 + 256;

    if (ws_size < need) {
        hipMemsetAsync(d_out, 0, (size_t)out_size * sizeof(float), stream);
        long long total = (long long)n_edges * 32;
        edge_scatter_fallback<<<(int)((total + 255) / 256), 256, 0, stream>>>(
            ge, weight, e_feat, src, dst, out, n_edges);
        return;
    }

    char* ws = (char*)d_ws;
    _Float16*     emb     = (_Float16*)(ws + o_emb);
    int*          counts  = (int*)(ws + o_counts);
    int*          ovf_cnt = (int*)(ws + o_ovfcnt);
    unsigned int* bucket  = (unsigned int*)(ws + o_bucket);
    int*          ovf     = (int*)(ws + o_ovf);

    // One memset covers counts + ovf_cnt (contiguous slabs).
    hipMemsetAsync(counts, 0, (o_bucket - o_counts), stream);

    // Fused pre-pass: ~31% of blocks do edges, rest do emb.
    const int GRID = 2048;
    int eb = 640;
    fused_pre_kernel<<<GRID, NT, 0, stream>>>(ge, weight, e_feat, src, dst,
                                              emb, counts, bucket, ovf_cnt, ovf,
                                              n_nodes, n_edges, eb);

    long long total = (long long)n_nodes * 32;
    gather_kernel<<<(int)((total + 255) / 256), NT, 0, stream>>>(
        emb, counts, bucket, ovf_cnt, ovf, out, n_nodes);
}